// Round 13
// baseline (139.152 us; speedup 1.0000x reference)
//
#include <hip/hip_runtime.h>
#include <cmath>

#define NPIX 16384
#define NATOM 1024
#define DIM 64
#define SPAR 8

// ---------------------------------------------------------------------------
// Fused pre-pass, grid-partitioned (1344 blocks) — unchanged (R9-verified):
//   [0,256):    G 64x64 tile = D^T D + 1e-4 I, fp64 acc; Gd diag
//   [256,320):  Dt transpose
//   [320,1344): HB 128n x 128k tile (fp32, 8x8/thread)
// ---------------------------------------------------------------------------
__global__ __launch_bounds__(256) void k_pre(const float* __restrict__ X,
                                             const float* __restrict__ D,
                                             float* __restrict__ G,
                                             float* __restrict__ Dt,
                                             float* __restrict__ Gd,
                                             float* __restrict__ HB) {
  __shared__ float smem[2 * DIM * 128];  // 64 KiB
  const int b = blockIdx.x;
  if (b < 256) {
    const int i0 = (b >> 4) * 64, j0 = (b & 15) * 64;
    float(*sA)[65] = (float(*)[65])smem;
    float(*sB)[65] = (float(*)[65])(smem + DIM * 65);
    for (int t = threadIdx.x; t < DIM * 16; t += 256) {
      int d = t >> 4, c4 = (t & 15) * 4;
      *reinterpret_cast<float4*>(&sA[d][c4]) =
          *reinterpret_cast<const float4*>(&D[(size_t)d * NATOM + i0 + c4]);
      *reinterpret_cast<float4*>(&sB[d][c4]) =
          *reinterpret_cast<const float4*>(&D[(size_t)d * NATOM + j0 + c4]);
    }
    __syncthreads();
    const int ty = (threadIdx.x >> 4) * 4;
    const int tx = (threadIdx.x & 15) * 4;
    double acc[4][4];
#pragma unroll
    for (int ii = 0; ii < 4; ++ii)
#pragma unroll
      for (int jj = 0; jj < 4; ++jj) acc[ii][jj] = 0.0;
    for (int d = 0; d < DIM; ++d) {
      float a[4], bb[4];
#pragma unroll
      for (int ii = 0; ii < 4; ++ii) a[ii] = sA[d][ty + ii];
#pragma unroll
      for (int jj = 0; jj < 4; ++jj) bb[jj] = sB[d][tx + jj];
#pragma unroll
      for (int ii = 0; ii < 4; ++ii)
#pragma unroll
        for (int jj = 0; jj < 4; ++jj)
          acc[ii][jj] += (double)a[ii] * (double)bb[jj];
    }
#pragma unroll
    for (int ii = 0; ii < 4; ++ii)
#pragma unroll
      for (int jj = 0; jj < 4; ++jj) {
        const int k1 = i0 + ty + ii, k2 = j0 + tx + jj;
        float g = (float)acc[ii][jj];
        if (k1 == k2) {
          g += 1e-4f;
          Gd[k1] = g;
        }
        G[(size_t)k1 * NATOM + k2] = g;
      }
  } else if (b < 320) {
    const int base = (b - 256) * 1024 + threadIdx.x * 4;
    float4 v = *reinterpret_cast<const float4*>(&D[base]);
    const float vv[4] = {v.x, v.y, v.z, v.w};
#pragma unroll
    for (int e = 0; e < 4; ++e) {
      int idx = base + e;
      Dt[(size_t)(idx & (NATOM - 1)) * DIM + (idx >> 10)] = vv[e];
    }
  } else {
    const int bx = b - 320;
    const int n0 = (bx & 127) * 128, k0 = (bx >> 7) * 128;
    float(*sX)[128] = (float(*)[128])smem;
    float(*sD)[128] = (float(*)[128])(smem + DIM * 128);
    for (int i = threadIdx.x; i < DIM * 32; i += 256) {
      int d = i >> 5, c4 = (i & 31) * 4;
      *reinterpret_cast<float4*>(&sX[d][c4]) =
          *reinterpret_cast<const float4*>(&X[(size_t)d * NPIX + n0 + c4]);
      *reinterpret_cast<float4*>(&sD[d][c4]) =
          *reinterpret_cast<const float4*>(&D[(size_t)d * NATOM + k0 + c4]);
    }
    __syncthreads();
    const int nl = (threadIdx.x & 15) * 8;
    const int kl = (threadIdx.x >> 4) * 8;
    float acc[8][8];
#pragma unroll
    for (int i = 0; i < 8; ++i)
#pragma unroll
      for (int j = 0; j < 8; ++j) acc[i][j] = 0.f;
#pragma unroll 4
    for (int d = 0; d < DIM; ++d) {
      float xv[8], dv[8];
      *reinterpret_cast<float4*>(&xv[0]) = *reinterpret_cast<float4*>(&sX[d][nl]);
      *reinterpret_cast<float4*>(&xv[4]) = *reinterpret_cast<float4*>(&sX[d][nl + 4]);
      *reinterpret_cast<float4*>(&dv[0]) = *reinterpret_cast<float4*>(&sD[d][kl]);
      *reinterpret_cast<float4*>(&dv[4]) = *reinterpret_cast<float4*>(&sD[d][kl + 4]);
#pragma unroll
      for (int i = 0; i < 8; ++i)
#pragma unroll
        for (int j = 0; j < 8; ++j) acc[i][j] = fmaf(xv[i], dv[j], acc[i][j]);
    }
#pragma unroll
    for (int i = 0; i < 8; ++i)
#pragma unroll
      for (int j = 0; j < 2; ++j)
        *reinterpret_cast<float4*>(
            &HB[(size_t)(n0 + nl + i) * NATOM + k0 + kl + j * 4]) =
            *reinterpret_cast<float4*>(&acc[i][j * 4]);
  }
}

// ---------------------------------------------------------------------------
// DPP wave64 max-reduce (VALU latency, no LDS). HW-verified (rounds 6-12).
// ---------------------------------------------------------------------------
template <int CTRL>
__device__ __forceinline__ float dpp_fmax(float x) {
  int s = __builtin_amdgcn_update_dpp(__float_as_int(x), __float_as_int(x),
                                      CTRL, 0xf, 0xf, false);
  return fmaxf(x, __int_as_float(s));
}
__device__ __forceinline__ float wave_max_bcast(float x) {
  x = dpp_fmax<0x111>(x);  // row_shr:1
  x = dpp_fmax<0x112>(x);  // row_shr:2
  x = dpp_fmax<0x114>(x);  // row_shr:4
  x = dpp_fmax<0x118>(x);  // row_shr:8
  x = dpp_fmax<0x142>(x);  // row_bcast:15
  x = dpp_fmax<0x143>(x);  // row_bcast:31
  return __int_as_float(__builtin_amdgcn_readlane(__float_as_int(x), 63));
}

// ---------------------------------------------------------------------------
// Batched OMP, FOUR WAVES PER PIXEL (256-thread block), deduped solve.
// Wave w owns atoms [w*256, w*256+256); lane owns k = w*256+lane*4+j.
// Each wave: scores on its quarter + local DPP argmax (per-atom fp chains
// identical to all passing rounds). Barrier A: 4-way combine in LDS —
// M* = exact fmax of wave maxima, index = min cand among waves achieving M*
// (global first occurrence == np.argmax). SOLVER WAVE = n&3 (rotates so the
// serial solve chains spread across SIMDs) runs Cholesky + solves and
// publishes coefF via LDS; barrier B; other waves copy bit-exact values.
// Row fetches are issued before barrier B so latency hides under the solve.
// ---------------------------------------------------------------------------
__global__ __launch_bounds__(256, 4) void k_omp4(const float* __restrict__ HB,
                                                 const float* __restrict__ Dt,
                                                 const float* __restrict__ G,
                                                 const float* __restrict__ Gd,
                                                 float* __restrict__ out) {
  const int lane = threadIdx.x & 63;
  const int wave = threadIdx.x >> 6;
  const int kbase = wave * 256 + lane * 4;
  const int n = __builtin_amdgcn_readfirstlane(blockIdx.x);
  const int sv = n & 3;  // solver wave (rotates per pixel)

  __shared__ float sM[2][4];
  __shared__ int sC[2][4];
  __shared__ float sCoef[SPAR];

  float hb[4];
  {
    float4 v = *reinterpret_cast<const float4*>(&HB[(size_t)n * NATOM + kbase]);
    hb[0] = v.x; hb[1] = v.y; hb[2] = v.z; hb[3] = v.w;
  }
#pragma unroll
  for (int j = 0; j < 4; ++j) asm volatile("" : "+v"(hb[j]));

  int selI[SPAR];            // wave-uniform -> SGPRs
  float rows[SPAR - 1][4];   // rows[i][j] = G[selI[i]][kbase+j], pinned
  float Lm[SPAR][SPAR], invL[SPAR], ysel[SPAR], coefF[SPAR];

#pragma unroll 8
  for (int s = 0; s < SPAR; ++s) {
    // ---- h = hb - sum_i coef_i * rows_i (ascending i; same chains) ----
    float h[4];
#pragma unroll
    for (int j = 0; j < 4; ++j) {
      float hv = hb[j];
#pragma unroll
      for (int i = 0; i < SPAR - 1; ++i)
        if (i < s) hv = fmaf(-coefF[i], rows[i][j], hv);
      h[j] = hv;
    }
    // ---- local wave max of |h| (exact; fmaxf ignores NaN poison) ----
    const float Mw = wave_max_bcast(
        fmaxf(fmaxf(fabsf(h[0]), fabsf(h[1])), fmaxf(fabsf(h[2]), fabsf(h[3]))));
    // ---- local first match (descending j: last write = min j) ----
    unsigned cand = NATOM;
#pragma unroll
    for (int j = 3; j >= 0; --j)
      cand = (fabsf(h[j]) == Mw) ? (unsigned)(kbase + j) : cand;
    unsigned long long bal = __ballot(cand != (unsigned)NATOM);
    const int fl = __ffsll(bal) - 1;
    const int cw = __builtin_amdgcn_readlane((int)cand, fl);
    if (lane == 0) {
      sM[s & 1][wave] = Mw;
      sC[s & 1][wave] = cw;
    }
    __syncthreads();  // A
    // ---- 4-way combine: exact max, then min index among achievers ----
    const float Ma = sM[s & 1][0], Mb = sM[s & 1][1];
    const float Mc = sM[s & 1][2], Md = sM[s & 1][3];
    const float Ms = fmaxf(fmaxf(Ma, Mb), fmaxf(Mc, Md));
    int bkv = NATOM;
    {
      int c;
      c = (Ma == Ms) ? sC[s & 1][0] : NATOM; bkv = c < bkv ? c : bkv;
      c = (Mb == Ms) ? sC[s & 1][1] : NATOM; bkv = c < bkv ? c : bkv;
      c = (Mc == Ms) ? sC[s & 1][2] : NATOM; bkv = c < bkv ? c : bkv;
      c = (Md == Ms) ? sC[s & 1][3] : NATOM; bkv = c < bkv ? c : bkv;
    }
    const int bk = __builtin_amdgcn_readfirstlane(bkv);
    selI[s] = bk;

    // poison the selected slot in its owning wave/lane (NaN semantics)
    if ((bk >> 8) == wave && lane == ((bk >> 2) & 63)) {
#pragma unroll
      for (int j = 0; j < 4; ++j)
        if (j == (bk & 3)) hb[j] = __builtin_nanf("");
    }

    // issue new-row fetch BEFORE barrier B: latency hides under the solve
    if (s < SPAR - 1) {
      float4 rv = *reinterpret_cast<const float4*>(
          &G[(size_t)bk * NATOM + kbase]);
      rows[s][0] = rv.x; rows[s][1] = rv.y;
      rows[s][2] = rv.z; rows[s][3] = rv.w;
    }

    if (wave == sv) {
      // ---- Cholesky update (single wave; identical fp ops) ----
      const float hbs = HB[(size_t)n * NATOM + bk];  // uniform scalar load
      const float diag = Gd[bk];                     // uniform scalar load
      float w[SPAR];
      float sq = 0.f;
#pragma unroll
      for (int i = 0; i < SPAR; ++i)
        if (i < s) {
          float a = G[(size_t)selI[i] * NATOM + bk];  // uniform scalar load
#pragma unroll
          for (int t = 0; t < SPAR; ++t)
            if (t < i) a = fmaf(-Lm[i][t], w[t], a);
          w[i] = a * invL[i];
          sq += w[i] * w[i];
          Lm[s][i] = w[i];
        }
      float cc = diag - sq;
      if (cc < 1e-6f) cc = 1e-6f;  // jnp.clip(..., CHOL_EPS)
      invL[s] = 1.0f / sqrtf(cc);

      // ---- y_s (incremental forward solve) ----
      {
        float a = hbs;
#pragma unroll
        for (int t = 0; t < SPAR; ++t)
          if (t < s) a = fmaf(-Lm[s][t], ysel[t], a);
        ysel[s] = a * invL[s];
      }
      // ---- coef: backward solve L^T x = y ----
#pragma unroll
      for (int i = SPAR - 1; i >= 0; --i)
        if (i <= s) {
          float a = ysel[i];
#pragma unroll
          for (int t = 0; t < SPAR; ++t)
            if (t > i && t <= s) a = fmaf(-Lm[t][i], coefF[t], a);
          coefF[i] = a * invL[i];
        }
      // publish bit-exact coefs
      if (lane == 0) {
#pragma unroll
        for (int i = 0; i < SPAR; ++i)
          if (i <= s) sCoef[i] = coefF[i];
      }
    }
    __syncthreads();  // B
    if (wave != sv) {
#pragma unroll
      for (int i = 0; i < SPAR; ++i)
        if (i <= s) coefF[i] = sCoef[i];
    }

    // pin the fetched row: residency + post-solve waitcnt placement
    if (s < SPAR - 1) {
#pragma unroll
      for (int j = 0; j < 4; ++j) asm volatile("" : "+v"(rows[s][j]));
    }
  }

  // ---- outputs (rotated off the solver wave) ----
  if (wave == ((sv + 1) & 3)) {  // recon [n][64]
    double r = 0.0;
#pragma unroll
    for (int i = 0; i < SPAR; ++i)
      r += (double)coefF[i] * (double)Dt[(size_t)selI[i] * DIM + lane];
    out[(size_t)n * DIM + lane] = (float)r;
  } else if (wave == ((sv + 2) & 3)) {  // I and coeffs [n][8]
    float fi = 0.f, fc = 0.f;
#pragma unroll
    for (int i = 0; i < SPAR; ++i)
      if (lane == i) { fi = (float)selI[i]; fc = coefF[i]; }
    if (lane < SPAR) {
      out[(size_t)NPIX * DIM + (size_t)n * SPAR + lane] = fi;
      out[(size_t)NPIX * DIM + (size_t)NPIX * SPAR + (size_t)n * SPAR + lane] = fc;
    }
  }
}

// ---------------------------------------------------------------------------
// Fallback single-wave OMP (tiny-workspace path; R10 kernel). Unchanged.
// ---------------------------------------------------------------------------
__global__ __launch_bounds__(64) void k_omp_fb(const float* __restrict__ X,
                                               const float* __restrict__ D,
                                               const float* __restrict__ G,
                                               const float* __restrict__ Gd,
                                               float* __restrict__ out) {
  const int lane = threadIdx.x & 63;
  const int lane16 = lane * 16;
  const int n = __builtin_amdgcn_readfirstlane(blockIdx.x);

  float hb[16];
  {
    double a[16];
#pragma unroll
    for (int j = 0; j < 16; ++j) a[j] = 0.0;
    for (int d = 0; d < DIM; ++d) {
      float xd = X[(size_t)d * NPIX + n];
#pragma unroll
      for (int j = 0; j < 16; ++j)
        a[j] += (double)xd * (double)D[(size_t)d * NATOM + lane16 + j];
    }
#pragma unroll
    for (int j = 0; j < 16; ++j) hb[j] = (float)a[j];
  }
#pragma unroll
  for (int j = 0; j < 16; ++j) asm volatile("" : "+v"(hb[j]));

  int selI[SPAR];
  float rows[SPAR - 1][16];
  float Lm[SPAR][SPAR], invL[SPAR], ysel[SPAR], coefF[SPAR];

#pragma unroll 8
  for (int s = 0; s < SPAR; ++s) {
    float h[16];
#pragma unroll
    for (int j = 0; j < 16; ++j) {
      float hv = hb[j];
#pragma unroll
      for (int i = 0; i < SPAR - 1; ++i)
        if (i < s) hv = fmaf(-coefF[i], rows[i][j], hv);
      h[j] = hv;
    }
    float m0 = fmaxf(fmaxf(fmaxf(fabsf(h[0]), fabsf(h[1])), fabsf(h[2])), fabsf(h[3]));
    float m1 = fmaxf(fmaxf(fmaxf(fabsf(h[4]), fabsf(h[5])), fabsf(h[6])), fabsf(h[7]));
    float m2 = fmaxf(fmaxf(fmaxf(fabsf(h[8]), fabsf(h[9])), fabsf(h[10])), fabsf(h[11]));
    float m3 = fmaxf(fmaxf(fmaxf(fabsf(h[12]), fabsf(h[13])), fabsf(h[14])), fabsf(h[15]));
    const float M = wave_max_bcast(fmaxf(fmaxf(m0, m1), fmaxf(m2, m3)));
    unsigned cand = NATOM;
#pragma unroll
    for (int j = 15; j >= 0; --j)
      cand = (fabsf(h[j]) == M) ? (unsigned)(lane16 + j) : cand;
    unsigned long long bal = __ballot(cand != (unsigned)NATOM);
    const int fl = __ffsll(bal) - 1;
    const int bk = __builtin_amdgcn_readlane((int)cand, fl);
    selI[s] = bk;
    const int bl = bk >> 4, bj = bk & 15;

    float v = 0.f;
#pragma unroll
    for (int j = 0; j < 16; ++j)
      if (j == bj) v = hb[j];
    const float hbs =
        __int_as_float(__builtin_amdgcn_readlane(__float_as_int(v), bl));

#pragma unroll
    for (int j = 0; j < 16; ++j)
      if (j == bj && lane == bl) hb[j] = __builtin_nanf("");

    if (s < SPAR - 1) {
#pragma unroll
      for (int q = 0; q < 4; ++q) {
        float4 rv = *reinterpret_cast<const float4*>(
            &G[(size_t)bk * NATOM + lane16 + q * 4]);
        rows[s][q * 4 + 0] = rv.x; rows[s][q * 4 + 1] = rv.y;
        rows[s][q * 4 + 2] = rv.z; rows[s][q * 4 + 3] = rv.w;
      }
    }

    const float diag = Gd[bk];
    float w[SPAR];
    float sq = 0.f;
#pragma unroll
    for (int i = 0; i < SPAR; ++i)
      if (i < s) {
        float a = G[(size_t)selI[i] * NATOM + bk];
#pragma unroll
        for (int t = 0; t < SPAR; ++t)
          if (t < i) a = fmaf(-Lm[i][t], w[t], a);
        w[i] = a * invL[i];
        sq += w[i] * w[i];
        Lm[s][i] = w[i];
      }
    float cc = diag - sq;
    if (cc < 1e-6f) cc = 1e-6f;
    invL[s] = 1.0f / sqrtf(cc);
    {
      float a = hbs;
#pragma unroll
      for (int t = 0; t < SPAR; ++t)
        if (t < s) a = fmaf(-Lm[s][t], ysel[t], a);
      ysel[s] = a * invL[s];
    }
#pragma unroll
    for (int i = SPAR - 1; i >= 0; --i)
      if (i <= s) {
        float a = ysel[i];
#pragma unroll
        for (int t = 0; t < SPAR; ++t)
          if (t > i && t <= s) a = fmaf(-Lm[t][i], coefF[t], a);
        coefF[i] = a * invL[i];
      }
    if (s < SPAR - 1) {
#pragma unroll
      for (int j = 0; j < 16; ++j) asm volatile("" : "+v"(rows[s][j]));
    }
  }

  double r = 0.0;
#pragma unroll
  for (int i = 0; i < SPAR; ++i)
    r += (double)coefF[i] * (double)D[(size_t)lane * NATOM + selI[i]];
  out[(size_t)n * DIM + lane] = (float)r;

  float fi = 0.f, fc = 0.f;
#pragma unroll
  for (int i = 0; i < SPAR; ++i)
    if (lane == i) { fi = (float)selI[i]; fc = coefF[i]; }
  if (lane < SPAR) {
    out[(size_t)NPIX * DIM + (size_t)n * SPAR + lane] = fi;
    out[(size_t)NPIX * DIM + (size_t)NPIX * SPAR + (size_t)n * SPAR + lane] = fc;
  }
}

__global__ __launch_bounds__(256) void k_gram(const float* __restrict__ D,
                                              float* __restrict__ G,
                                              float* __restrict__ Gd) {
  int k1 = blockIdx.x;
  __shared__ float d1[DIM];
  if (threadIdx.x < DIM) d1[threadIdx.x] = D[(size_t)threadIdx.x * NATOM + k1];
  __syncthreads();
  for (int k2 = threadIdx.x; k2 < NATOM; k2 += 256) {
    double acc = 0.0;
#pragma unroll
    for (int d = 0; d < DIM; ++d)
      acc += (double)d1[d] * (double)D[(size_t)d * NATOM + k2];
    float g = (float)acc;
    if (k2 == k1) {
      g += 1e-4f;
      Gd[k1] = g;
    }
    G[(size_t)k1 * NATOM + k2] = g;
  }
}

extern "C" void kernel_launch(void* const* d_in, const int* in_sizes, int n_in,
                              void* d_out, int out_size, void* d_ws,
                              size_t ws_size, hipStream_t stream) {
  const float* X = (const float*)d_in[0];  // [64, 16384]
  const float* D = (const float*)d_in[1];  // [64, 1024]
  float* out = (float*)d_out;              // [recon | I | coeffs] as fp32
  float* G = (float*)d_ws;                 // 4 MB
  float* Dt = G + (size_t)NATOM * NATOM;   // 256 KB
  float* Gd = Dt + (size_t)NATOM * DIM;    // 4 KB
  float* HB = Gd + NATOM;                  // 64 MB
  const size_t needFull =
      ((size_t)NATOM * NATOM + (size_t)NATOM * DIM + NATOM +
       (size_t)NPIX * NATOM) * sizeof(float);

  if (ws_size >= needFull) {
    k_pre<<<dim3(1344), dim3(256), 0, stream>>>(X, D, G, Dt, Gd, HB);
    k_omp4<<<dim3(NPIX), dim3(256), 0, stream>>>(HB, Dt, G, Gd, out);
  } else {
    k_gram<<<dim3(NATOM), dim3(256), 0, stream>>>(D, G, Gd);
    k_omp_fb<<<dim3(NPIX), dim3(64), 0, stream>>>(X, D, G, Gd, out);
  }
}

// Round 14
// 112.351 us; speedup vs baseline: 1.2385x; 1.2385x over previous
//
#include <hip/hip_runtime.h>
#include <cmath>

#define NPIX 16384
#define NATOM 1024
#define DIM 64
#define SPAR 8

typedef float f32x2 __attribute__((ext_vector_type(2)));

// ---------------------------------------------------------------------------
// Fused pre-pass, grid-partitioned (1344 blocks) — unchanged (R9-verified):
//   [0,256):    G 64x64 tile = D^T D + 1e-4 I, fp64 acc; Gd diag
//   [256,320):  Dt transpose
//   [320,1344): HB 128n x 128k tile (fp32, 8x8/thread)
// ---------------------------------------------------------------------------
__global__ __launch_bounds__(256) void k_pre(const float* __restrict__ X,
                                             const float* __restrict__ D,
                                             float* __restrict__ G,
                                             float* __restrict__ Dt,
                                             float* __restrict__ Gd,
                                             float* __restrict__ HB) {
  __shared__ float smem[2 * DIM * 128];  // 64 KiB
  const int b = blockIdx.x;
  if (b < 256) {
    const int i0 = (b >> 4) * 64, j0 = (b & 15) * 64;
    float(*sA)[65] = (float(*)[65])smem;
    float(*sB)[65] = (float(*)[65])(smem + DIM * 65);
    for (int t = threadIdx.x; t < DIM * 16; t += 256) {
      int d = t >> 4, c4 = (t & 15) * 4;
      *reinterpret_cast<float4*>(&sA[d][c4]) =
          *reinterpret_cast<const float4*>(&D[(size_t)d * NATOM + i0 + c4]);
      *reinterpret_cast<float4*>(&sB[d][c4]) =
          *reinterpret_cast<const float4*>(&D[(size_t)d * NATOM + j0 + c4]);
    }
    __syncthreads();
    const int ty = (threadIdx.x >> 4) * 4;
    const int tx = (threadIdx.x & 15) * 4;
    double acc[4][4];
#pragma unroll
    for (int ii = 0; ii < 4; ++ii)
#pragma unroll
      for (int jj = 0; jj < 4; ++jj) acc[ii][jj] = 0.0;
    for (int d = 0; d < DIM; ++d) {
      float a[4], bb[4];
#pragma unroll
      for (int ii = 0; ii < 4; ++ii) a[ii] = sA[d][ty + ii];
#pragma unroll
      for (int jj = 0; jj < 4; ++jj) bb[jj] = sB[d][tx + jj];
#pragma unroll
      for (int ii = 0; ii < 4; ++ii)
#pragma unroll
        for (int jj = 0; jj < 4; ++jj)
          acc[ii][jj] += (double)a[ii] * (double)bb[jj];
    }
#pragma unroll
    for (int ii = 0; ii < 4; ++ii)
#pragma unroll
      for (int jj = 0; jj < 4; ++jj) {
        const int k1 = i0 + ty + ii, k2 = j0 + tx + jj;
        float g = (float)acc[ii][jj];
        if (k1 == k2) {
          g += 1e-4f;
          Gd[k1] = g;
        }
        G[(size_t)k1 * NATOM + k2] = g;
      }
  } else if (b < 320) {
    const int base = (b - 256) * 1024 + threadIdx.x * 4;
    float4 v = *reinterpret_cast<const float4*>(&D[base]);
    const float vv[4] = {v.x, v.y, v.z, v.w};
#pragma unroll
    for (int e = 0; e < 4; ++e) {
      int idx = base + e;
      Dt[(size_t)(idx & (NATOM - 1)) * DIM + (idx >> 10)] = vv[e];
    }
  } else {
    const int bx = b - 320;
    const int n0 = (bx & 127) * 128, k0 = (bx >> 7) * 128;
    float(*sX)[128] = (float(*)[128])smem;
    float(*sD)[128] = (float(*)[128])(smem + DIM * 128);
    for (int i = threadIdx.x; i < DIM * 32; i += 256) {
      int d = i >> 5, c4 = (i & 31) * 4;
      *reinterpret_cast<float4*>(&sX[d][c4]) =
          *reinterpret_cast<const float4*>(&X[(size_t)d * NPIX + n0 + c4]);
      *reinterpret_cast<float4*>(&sD[d][c4]) =
          *reinterpret_cast<const float4*>(&D[(size_t)d * NATOM + k0 + c4]);
    }
    __syncthreads();
    const int nl = (threadIdx.x & 15) * 8;
    const int kl = (threadIdx.x >> 4) * 8;
    float acc[8][8];
#pragma unroll
    for (int i = 0; i < 8; ++i)
#pragma unroll
      for (int j = 0; j < 8; ++j) acc[i][j] = 0.f;
#pragma unroll 4
    for (int d = 0; d < DIM; ++d) {
      float xv[8], dv[8];
      *reinterpret_cast<float4*>(&xv[0]) = *reinterpret_cast<float4*>(&sX[d][nl]);
      *reinterpret_cast<float4*>(&xv[4]) = *reinterpret_cast<float4*>(&sX[d][nl + 4]);
      *reinterpret_cast<float4*>(&dv[0]) = *reinterpret_cast<float4*>(&sD[d][kl]);
      *reinterpret_cast<float4*>(&dv[4]) = *reinterpret_cast<float4*>(&sD[d][kl + 4]);
#pragma unroll
      for (int i = 0; i < 8; ++i)
#pragma unroll
        for (int j = 0; j < 8; ++j) acc[i][j] = fmaf(xv[i], dv[j], acc[i][j]);
    }
#pragma unroll
    for (int i = 0; i < 8; ++i)
#pragma unroll
      for (int j = 0; j < 2; ++j)
        *reinterpret_cast<float4*>(
            &HB[(size_t)(n0 + nl + i) * NATOM + k0 + kl + j * 4]) =
            *reinterpret_cast<float4*>(&acc[i][j * 4]);
  }
}

// ---------------------------------------------------------------------------
// DPP wave64 max-reduce (VALU latency, no LDS). HW-verified (rounds 6-13).
// ---------------------------------------------------------------------------
template <int CTRL>
__device__ __forceinline__ float dpp_fmax(float x) {
  int s = __builtin_amdgcn_update_dpp(__float_as_int(x), __float_as_int(x),
                                      CTRL, 0xf, 0xf, false);
  return fmaxf(x, __int_as_float(s));
}
__device__ __forceinline__ float wave_max_bcast(float x) {
  x = dpp_fmax<0x111>(x);  // row_shr:1
  x = dpp_fmax<0x112>(x);  // row_shr:2
  x = dpp_fmax<0x114>(x);  // row_shr:4
  x = dpp_fmax<0x118>(x);  // row_shr:8
  x = dpp_fmax<0x142>(x);  // row_bcast:15
  x = dpp_fmax<0x143>(x);  // row_bcast:31
  return __int_as_float(__builtin_amdgcn_readlane(__float_as_int(x), 63));
}

// packed fp32 fma: d = fma(a, b, d) per half — fused, bit-identical per elem
__device__ __forceinline__ void pk_fma(f32x2& d, f32x2 a, f32x2 b) {
  asm("v_pk_fma_f32 %0, %1, %2, %0" : "+v"(d) : "v"(a), "v"(b));
}

// ---------------------------------------------------------------------------
// Batched OMP: ONE WAVE PER PIXEL (R10 structure — lowest measured
// instruction count). Lane owns atoms k = lane*16+j. Pinned rows in regs.
// Score FMAs in packed fp32 pairs (v_pk_fma_f32): per-element op and order
// identical to R10's scalar fmaf chain. Cholesky column s_loads batched.
// Argmax: exact f32 DPP wave-max (abs folded), descending-j first-match,
// ballot+ffs+readlane. NaN-poison masking. hbs/diag via uniform loads.
// ---------------------------------------------------------------------------
template <bool HBWS, bool DTW>
__global__ __launch_bounds__(64) void k_omp(const float* __restrict__ HB,
                                            const float* __restrict__ X,
                                            const float* __restrict__ D,
                                            const float* __restrict__ Dt,
                                            const float* __restrict__ G,
                                            const float* __restrict__ Gd,
                                            float* __restrict__ out) {
  const int lane = threadIdx.x & 63;
  const int lane16 = lane * 16;
  const int n = __builtin_amdgcn_readfirstlane(blockIdx.x);

  f32x2 hb2[8];
  if (HBWS) {
#pragma unroll
    for (int q = 0; q < 4; ++q) {
      float4 v = *reinterpret_cast<const float4*>(
          &HB[(size_t)n * NATOM + lane16 + q * 4]);
      f32x2 a = {v.x, v.y}, b = {v.z, v.w};
      hb2[q * 2] = a;
      hb2[q * 2 + 1] = b;
    }
  } else {
    double a[16];
#pragma unroll
    for (int j = 0; j < 16; ++j) a[j] = 0.0;
    for (int d = 0; d < DIM; ++d) {
      float xd = X[(size_t)d * NPIX + n];
#pragma unroll
      for (int j = 0; j < 16; ++j)
        a[j] += (double)xd * (double)D[(size_t)d * NATOM + lane16 + j];
    }
#pragma unroll
    for (int j = 0; j < 16; ++j) hb2[j >> 1][j & 1] = (float)a[j];
  }
#pragma unroll
  for (int q = 0; q < 8; ++q) asm volatile("" : "+v"(hb2[q]));

  int selI[SPAR];              // wave-uniform -> SGPRs
  f32x2 rows2[SPAR - 1][8];    // rows2[i][jj] = G[selI[i]][lane16+2jj..+1]
  float Lm[SPAR][SPAR], invL[SPAR], ysel[SPAR], coefF[SPAR];

#pragma unroll 8
  for (int s = 0; s < SPAR; ++s) {
    // ---- h = hb - sum_i coef_i * rows_i (packed; ascending i) ----
    f32x2 h2[8];
#pragma unroll
    for (int q = 0; q < 8; ++q) h2[q] = hb2[q];
#pragma unroll
    for (int i = 0; i < SPAR - 1; ++i)
      if (i < s) {
        const float nc = -coefF[i];
        const f32x2 c2 = {nc, nc};
#pragma unroll
        for (int q = 0; q < 8; ++q) pk_fma(h2[q], c2, rows2[i][q]);
      }
    // ---- wave max of |h| (abs folds into v_max input modifiers) ----
    float m0 = fmaxf(fmaxf(fabsf(h2[0][0]), fabsf(h2[0][1])),
                     fmaxf(fabsf(h2[1][0]), fabsf(h2[1][1])));
    float m1 = fmaxf(fmaxf(fabsf(h2[2][0]), fabsf(h2[2][1])),
                     fmaxf(fabsf(h2[3][0]), fabsf(h2[3][1])));
    float m2 = fmaxf(fmaxf(fabsf(h2[4][0]), fabsf(h2[4][1])),
                     fmaxf(fabsf(h2[5][0]), fabsf(h2[5][1])));
    float m3 = fmaxf(fmaxf(fabsf(h2[6][0]), fabsf(h2[6][1])),
                     fmaxf(fabsf(h2[7][0]), fabsf(h2[7][1])));
    const float M = wave_max_bcast(fmaxf(fmaxf(m0, m1), fmaxf(m2, m3)));
    // ---- in-lane first match (descending j: last write = min j) ----
    unsigned cand = NATOM;
#pragma unroll
    for (int j = 15; j >= 0; --j)
      cand = (fabsf(h2[j >> 1][j & 1]) == M) ? (unsigned)(lane16 + j) : cand;
    // ---- cross-lane: lowest lane with a match holds the global min idx ----
    unsigned long long bal = __ballot(cand != (unsigned)NATOM);
    const int fl = __ffsll(bal) - 1;
    const int bk = __builtin_amdgcn_readlane((int)cand, fl);  // wave-uniform
    selI[s] = bk;
    const int bl = bk >> 4, bj = bk & 15;

    // hbs: wave-uniform load from memory (never poisoned)
    float hbs;
    if (HBWS) {
      hbs = HB[(size_t)n * NATOM + bk];  // s_load, hidden under chol below
    } else {
      float v = 0.f;
#pragma unroll
      for (int j = 0; j < 16; ++j)
        if (j == bj) v = hb2[j >> 1][j & 1];
      hbs = __int_as_float(__builtin_amdgcn_readlane(__float_as_int(v), bl));
    }

    // poison the selected slot: it loses every future argmax (NaN semantics)
#pragma unroll
    for (int j = 0; j < 16; ++j)
      if (j == bj && lane == bl) hb2[j >> 1][j & 1] = __builtin_nanf("");

    // issue new-row fetch (dwordx4 x4); completes during chol/solve below
    if (s < SPAR - 1) {
#pragma unroll
      for (int q = 0; q < 4; ++q) {
        float4 rv = *reinterpret_cast<const float4*>(
            &G[(size_t)bk * NATOM + lane16 + q * 4]);
        f32x2 a = {rv.x, rv.y}, b = {rv.z, rv.w};
        rows2[s][q * 2] = a;
        rows2[s][q * 2 + 1] = b;
      }
    }

    // ---- Cholesky update: L_{s+1} = [[L, 0], [w^T, corner]] ----
    const float diag = Gd[bk];  // wave-uniform scalar load
    float colv[SPAR];
#pragma unroll
    for (int i = 0; i < SPAR; ++i)  // batch the uniform column loads
      if (i < s) colv[i] = G[(size_t)selI[i] * NATOM + bk];
    float w[SPAR];
    float sq = 0.f;
#pragma unroll
    for (int i = 0; i < SPAR; ++i)
      if (i < s) {
        float a = colv[i];
#pragma unroll
        for (int t = 0; t < SPAR; ++t)
          if (t < i) a = fmaf(-Lm[i][t], w[t], a);
        w[i] = a * invL[i];
        sq += w[i] * w[i];
        Lm[s][i] = w[i];
      }
    float cc = diag - sq;
    if (cc < 1e-6f) cc = 1e-6f;  // jnp.clip(..., CHOL_EPS)
    invL[s] = 1.0f / sqrtf(cc);  // Lm diag never stored (only invL is read)

    // ---- y_s (incremental forward solve) ----
    {
      float a = hbs;
#pragma unroll
      for (int t = 0; t < SPAR; ++t)
        if (t < s) a = fmaf(-Lm[s][t], ysel[t], a);
      ysel[s] = a * invL[s];
    }
    // ---- coef: backward solve L^T x = y ----
#pragma unroll
    for (int i = SPAR - 1; i >= 0; --i)
      if (i <= s) {
        float a = ysel[i];
#pragma unroll
        for (int t = 0; t < SPAR; ++t)
          if (t > i && t <= s) a = fmaf(-Lm[t][i], coefF[t], a);
        coefF[i] = a * invL[i];
      }

    // pin the fetched row: forces residency; waitcnt lands here (post-solve)
    if (s < SPAR - 1) {
#pragma unroll
      for (int q = 0; q < 8; ++q) asm volatile("" : "+v"(rows2[s][q]));
    }
  }

  // ---- outputs: recon [n][64], I [n][8], coeffs [n][8] ----
  double r = 0.0;
#pragma unroll
  for (int i = 0; i < SPAR; ++i) {
    float dv = DTW ? Dt[(size_t)selI[i] * DIM + lane]
                   : D[(size_t)lane * NATOM + selI[i]];
    r += (double)coefF[i] * (double)dv;
  }
  out[(size_t)n * DIM + lane] = (float)r;

  float fi = 0.f, fc = 0.f;
#pragma unroll
  for (int i = 0; i < SPAR; ++i)
    if (lane == i) { fi = (float)selI[i]; fc = coefF[i]; }
  if (lane < SPAR) {
    out[(size_t)NPIX * DIM + (size_t)n * SPAR + lane] = fi;
    out[(size_t)NPIX * DIM + (size_t)NPIX * SPAR + (size_t)n * SPAR + lane] = fc;
  }
}

// Standalone gram for the tiny-workspace fallback
__global__ __launch_bounds__(256) void k_gram(const float* __restrict__ D,
                                              float* __restrict__ G,
                                              float* __restrict__ Gd) {
  int k1 = blockIdx.x;
  __shared__ float d1[DIM];
  if (threadIdx.x < DIM) d1[threadIdx.x] = D[(size_t)threadIdx.x * NATOM + k1];
  __syncthreads();
  for (int k2 = threadIdx.x; k2 < NATOM; k2 += 256) {
    double acc = 0.0;
#pragma unroll
    for (int d = 0; d < DIM; ++d)
      acc += (double)d1[d] * (double)D[(size_t)d * NATOM + k2];
    float g = (float)acc;
    if (k2 == k1) {
      g += 1e-4f;
      Gd[k1] = g;
    }
    G[(size_t)k1 * NATOM + k2] = g;
  }
}

extern "C" void kernel_launch(void* const* d_in, const int* in_sizes, int n_in,
                              void* d_out, int out_size, void* d_ws,
                              size_t ws_size, hipStream_t stream) {
  const float* X = (const float*)d_in[0];  // [64, 16384]
  const float* D = (const float*)d_in[1];  // [64, 1024]
  float* out = (float*)d_out;              // [recon | I | coeffs] as fp32
  float* G = (float*)d_ws;                 // 4 MB
  float* Dt = G + (size_t)NATOM * NATOM;   // 256 KB
  float* Gd = Dt + (size_t)NATOM * DIM;    // 4 KB
  float* HB = Gd + NATOM;                  // 64 MB
  const size_t needFull =
      ((size_t)NATOM * NATOM + (size_t)NATOM * DIM + NATOM +
       (size_t)NPIX * NATOM) * sizeof(float);

  if (ws_size >= needFull) {
    k_pre<<<dim3(1344), dim3(256), 0, stream>>>(X, D, G, Dt, Gd, HB);
    k_omp<true, true><<<dim3(NPIX), dim3(64), 0, stream>>>(
        HB, X, D, Dt, G, Gd, out);
  } else {
    k_gram<<<dim3(NATOM), dim3(256), 0, stream>>>(D, G, Gd);
    k_omp<false, false><<<dim3(NPIX), dim3(64), 0, stream>>>(
        nullptr, X, D, nullptr, G, Gd, out);
  }
}

// Round 15
// 100.322 us; speedup vs baseline: 1.3871x; 1.1199x over previous
//
#include <hip/hip_runtime.h>
#include <cmath>

#define NPIX 16384
#define NATOM 1024
#define DIM 64
#define SPAR 8

// ---------------------------------------------------------------------------
// Fused pre-pass, grid-partitioned (1344 blocks) — unchanged (R9-verified):
//   [0,256):    G 64x64 tile = D^T D + 1e-4 I, fp64 acc; Gd diag
//   [256,320):  Dt transpose
//   [320,1344): HB 128n x 128k tile (fp32, 8x8/thread)
// ---------------------------------------------------------------------------
__global__ __launch_bounds__(256) void k_pre(const float* __restrict__ X,
                                             const float* __restrict__ D,
                                             float* __restrict__ G,
                                             float* __restrict__ Dt,
                                             float* __restrict__ Gd,
                                             float* __restrict__ HB) {
  __shared__ float smem[2 * DIM * 128];  // 64 KiB
  const int b = blockIdx.x;
  if (b < 256) {
    const int i0 = (b >> 4) * 64, j0 = (b & 15) * 64;
    float(*sA)[65] = (float(*)[65])smem;
    float(*sB)[65] = (float(*)[65])(smem + DIM * 65);
    for (int t = threadIdx.x; t < DIM * 16; t += 256) {
      int d = t >> 4, c4 = (t & 15) * 4;
      *reinterpret_cast<float4*>(&sA[d][c4]) =
          *reinterpret_cast<const float4*>(&D[(size_t)d * NATOM + i0 + c4]);
      *reinterpret_cast<float4*>(&sB[d][c4]) =
          *reinterpret_cast<const float4*>(&D[(size_t)d * NATOM + j0 + c4]);
    }
    __syncthreads();
    const int ty = (threadIdx.x >> 4) * 4;
    const int tx = (threadIdx.x & 15) * 4;
    double acc[4][4];
#pragma unroll
    for (int ii = 0; ii < 4; ++ii)
#pragma unroll
      for (int jj = 0; jj < 4; ++jj) acc[ii][jj] = 0.0;
    for (int d = 0; d < DIM; ++d) {
      float a[4], bb[4];
#pragma unroll
      for (int ii = 0; ii < 4; ++ii) a[ii] = sA[d][ty + ii];
#pragma unroll
      for (int jj = 0; jj < 4; ++jj) bb[jj] = sB[d][tx + jj];
#pragma unroll
      for (int ii = 0; ii < 4; ++ii)
#pragma unroll
        for (int jj = 0; jj < 4; ++jj)
          acc[ii][jj] += (double)a[ii] * (double)bb[jj];
    }
#pragma unroll
    for (int ii = 0; ii < 4; ++ii)
#pragma unroll
      for (int jj = 0; jj < 4; ++jj) {
        const int k1 = i0 + ty + ii, k2 = j0 + tx + jj;
        float g = (float)acc[ii][jj];
        if (k1 == k2) {
          g += 1e-4f;
          Gd[k1] = g;
        }
        G[(size_t)k1 * NATOM + k2] = g;
      }
  } else if (b < 320) {
    const int base = (b - 256) * 1024 + threadIdx.x * 4;
    float4 v = *reinterpret_cast<const float4*>(&D[base]);
    const float vv[4] = {v.x, v.y, v.z, v.w};
#pragma unroll
    for (int e = 0; e < 4; ++e) {
      int idx = base + e;
      Dt[(size_t)(idx & (NATOM - 1)) * DIM + (idx >> 10)] = vv[e];
    }
  } else {
    const int bx = b - 320;
    const int n0 = (bx & 127) * 128, k0 = (bx >> 7) * 128;
    float(*sX)[128] = (float(*)[128])smem;
    float(*sD)[128] = (float(*)[128])(smem + DIM * 128);
    for (int i = threadIdx.x; i < DIM * 32; i += 256) {
      int d = i >> 5, c4 = (i & 31) * 4;
      *reinterpret_cast<float4*>(&sX[d][c4]) =
          *reinterpret_cast<const float4*>(&X[(size_t)d * NPIX + n0 + c4]);
      *reinterpret_cast<float4*>(&sD[d][c4]) =
          *reinterpret_cast<const float4*>(&D[(size_t)d * NATOM + k0 + c4]);
    }
    __syncthreads();
    const int nl = (threadIdx.x & 15) * 8;
    const int kl = (threadIdx.x >> 4) * 8;
    float acc[8][8];
#pragma unroll
    for (int i = 0; i < 8; ++i)
#pragma unroll
      for (int j = 0; j < 8; ++j) acc[i][j] = 0.f;
#pragma unroll 4
    for (int d = 0; d < DIM; ++d) {
      float xv[8], dv[8];
      *reinterpret_cast<float4*>(&xv[0]) = *reinterpret_cast<float4*>(&sX[d][nl]);
      *reinterpret_cast<float4*>(&xv[4]) = *reinterpret_cast<float4*>(&sX[d][nl + 4]);
      *reinterpret_cast<float4*>(&dv[0]) = *reinterpret_cast<float4*>(&sD[d][kl]);
      *reinterpret_cast<float4*>(&dv[4]) = *reinterpret_cast<float4*>(&sD[d][kl + 4]);
#pragma unroll
      for (int i = 0; i < 8; ++i)
#pragma unroll
        for (int j = 0; j < 8; ++j) acc[i][j] = fmaf(xv[i], dv[j], acc[i][j]);
    }
#pragma unroll
    for (int i = 0; i < 8; ++i)
#pragma unroll
      for (int j = 0; j < 2; ++j)
        *reinterpret_cast<float4*>(
            &HB[(size_t)(n0 + nl + i) * NATOM + k0 + kl + j * 4]) =
            *reinterpret_cast<float4*>(&acc[i][j * 4]);
  }
}

// ---------------------------------------------------------------------------
// DPP wave64 max-reduce (VALU latency, no LDS). HW-verified (rounds 6-14).
// ---------------------------------------------------------------------------
template <int CTRL>
__device__ __forceinline__ float dpp_fmax(float x) {
  int s = __builtin_amdgcn_update_dpp(__float_as_int(x), __float_as_int(x),
                                      CTRL, 0xf, 0xf, false);
  return fmaxf(x, __int_as_float(s));
}
__device__ __forceinline__ float wave_max_bcast(float x) {
  x = dpp_fmax<0x111>(x);  // row_shr:1
  x = dpp_fmax<0x112>(x);  // row_shr:2
  x = dpp_fmax<0x114>(x);  // row_shr:4
  x = dpp_fmax<0x118>(x);  // row_shr:8
  x = dpp_fmax<0x142>(x);  // row_bcast:15
  x = dpp_fmax<0x143>(x);  // row_bcast:31
  return __int_as_float(__builtin_amdgcn_readlane(__float_as_int(x), 63));
}

// ---------------------------------------------------------------------------
// Batched OMP via Batch-OMP residual recurrence (Rubinstein et al.):
// maintain W = L^{-1} G_I rows (wr) and h with  h -= y_s * wr_s  per step —
// no per-step backward solve (one final solve for output coeffs, which is
// then op-identical to the previous rounds' final coeffs).
// ONE WAVE PER PIXEL, lane owns atoms k = lane*16+j; wr rows pinned in regs.
// Argmax: exact f32 DPP wave-max (abs folded), descending-j first-match,
// ballot+ffs+readlane == np.argmax first occurrence. NaN-poison h directly.
// hbs/diag/chol-column via wave-uniform scalar loads.
// ---------------------------------------------------------------------------
template <bool HBWS, bool DTW>
__global__ __launch_bounds__(64) void k_omp(const float* __restrict__ HB,
                                            const float* __restrict__ X,
                                            const float* __restrict__ D,
                                            const float* __restrict__ Dt,
                                            const float* __restrict__ G,
                                            const float* __restrict__ Gd,
                                            float* __restrict__ out) {
  const int lane = threadIdx.x & 63;
  const int lane16 = lane * 16;
  const int n = __builtin_amdgcn_readfirstlane(blockIdx.x);

  float h[16];  // residual correlations; starts as h_bar, updated in place
  if (HBWS) {
#pragma unroll
    for (int q = 0; q < 4; ++q) {
      float4 v = *reinterpret_cast<const float4*>(
          &HB[(size_t)n * NATOM + lane16 + q * 4]);
      h[q * 4 + 0] = v.x; h[q * 4 + 1] = v.y;
      h[q * 4 + 2] = v.z; h[q * 4 + 3] = v.w;
    }
  } else {
    double a[16];
#pragma unroll
    for (int j = 0; j < 16; ++j) a[j] = 0.0;
    for (int d = 0; d < DIM; ++d) {
      float xd = X[(size_t)d * NPIX + n];
#pragma unroll
      for (int j = 0; j < 16; ++j)
        a[j] += (double)xd * (double)D[(size_t)d * NATOM + lane16 + j];
    }
#pragma unroll
    for (int j = 0; j < 16; ++j) h[j] = (float)a[j];
  }
#pragma unroll
  for (int j = 0; j < 16; ++j) asm volatile("" : "+v"(h[j]));

  int selI[SPAR];            // wave-uniform -> SGPRs
  float wr[SPAR - 1][16];    // wr[t][j] = (L^{-1} G_I)[t][lane16+j], pinned
  float hbsel[SPAR];         // h_bar at selected atoms (for output path)
  float Lm[SPAR][SPAR], invL[SPAR], ysel[SPAR];

#pragma unroll 8
  for (int s = 0; s < SPAR; ++s) {
    // ---- argmax over |h| (NaN-poisoned slots lose: fmaxf ignores NaN) ----
    float m0 = fmaxf(fmaxf(fabsf(h[0]), fabsf(h[1])), fmaxf(fabsf(h[2]), fabsf(h[3])));
    float m1 = fmaxf(fmaxf(fabsf(h[4]), fabsf(h[5])), fmaxf(fabsf(h[6]), fabsf(h[7])));
    float m2 = fmaxf(fmaxf(fabsf(h[8]), fabsf(h[9])), fmaxf(fabsf(h[10]), fabsf(h[11])));
    float m3 = fmaxf(fmaxf(fabsf(h[12]), fabsf(h[13])), fmaxf(fabsf(h[14]), fabsf(h[15])));
    const float M = wave_max_bcast(fmaxf(fmaxf(m0, m1), fmaxf(m2, m3)));
    unsigned cand = NATOM;
#pragma unroll
    for (int j = 15; j >= 0; --j)
      cand = (fabsf(h[j]) == M) ? (unsigned)(lane16 + j) : cand;
    unsigned long long bal = __ballot(cand != (unsigned)NATOM);
    const int fl = __ffsll(bal) - 1;
    const int bk = __builtin_amdgcn_readlane((int)cand, fl);  // wave-uniform
    selI[s] = bk;
    const int bl = bk >> 4, bj = bk & 15;

    // poison the selected slot: loses every future argmax (NaN semantics)
#pragma unroll
    for (int j = 0; j < 16; ++j)
      if (j == bj && lane == bl) h[j] = __builtin_nanf("");

    // issue G-row fetch early; its waitcnt lands after the scalar chol below
    float g[16];
    if (s < SPAR - 1) {
#pragma unroll
      for (int q = 0; q < 4; ++q) {
        float4 rv = *reinterpret_cast<const float4*>(
            &G[(size_t)bk * NATOM + lane16 + q * 4]);
        g[q * 4 + 0] = rv.x; g[q * 4 + 1] = rv.y;
        g[q * 4 + 2] = rv.z; g[q * 4 + 3] = rv.w;
      }
    }

    // ---- scalar Cholesky column update (wave-uniform loads & math) ----
    const float hbs = HB ? HB[(size_t)n * NATOM + bk] : 0.f;
    hbsel[s] = hbs;
    const float diag = Gd[bk];
    float colv[SPAR];
#pragma unroll
    for (int i = 0; i < SPAR; ++i)
      if (i < s) colv[i] = G[(size_t)selI[i] * NATOM + bk];
    float w[SPAR];
    float sq = 0.f;
#pragma unroll
    for (int i = 0; i < SPAR; ++i)
      if (i < s) {
        float a = colv[i];
#pragma unroll
        for (int t = 0; t < SPAR; ++t)
          if (t < i) a = fmaf(-Lm[i][t], w[t], a);
        w[i] = a * invL[i];
        sq += w[i] * w[i];
        Lm[s][i] = w[i];
      }
    float cc = diag - sq;
    if (cc < 1e-6f) cc = 1e-6f;  // jnp.clip(..., CHOL_EPS)
    invL[s] = 1.0f / sqrtf(cc);

    // ---- y_s (incremental forward solve; earlier entries stable) ----
    {
      float a = hbs;
#pragma unroll
      for (int t = 0; t < SPAR; ++t)
        if (t < s) a = fmaf(-Lm[s][t], ysel[t], a);
      ysel[s] = a * invL[s];
    }

    // ---- build wr_s = (g - sum_t Lm[s][t]*wr_t) * invL[s]; h -= y_s*wr_s --
    if (s < SPAR - 1) {
#pragma unroll
      for (int j = 0; j < 16; ++j) {
        float a = g[j];
#pragma unroll
        for (int t = 0; t < SPAR - 1; ++t)
          if (t < s) a = fmaf(-Lm[s][t], wr[t][j], a);
        float v = a * invL[s];
        wr[s][j] = v;
        h[j] = fmaf(-ysel[s], v, h[j]);
      }
#pragma unroll
      for (int j = 0; j < 16; ++j) asm volatile("" : "+v"(wr[s][j]));
    }
  }

  // ---- final backward solve L^T c = y (op-identical to prior rounds) ----
  float coefF[SPAR];
#pragma unroll
  for (int i = SPAR - 1; i >= 0; --i) {
    float a = ysel[i];
#pragma unroll
    for (int t = 0; t < SPAR; ++t)
      if (t > i) a = fmaf(-Lm[t][i], coefF[t], a);
    coefF[i] = a * invL[i];
  }

  // ---- outputs: recon [n][64], I [n][8], coeffs [n][8] ----
  double r = 0.0;
#pragma unroll
  for (int i = 0; i < SPAR; ++i) {
    float dv = DTW ? Dt[(size_t)selI[i] * DIM + lane]
                   : D[(size_t)lane * NATOM + selI[i]];
    r += (double)coefF[i] * (double)dv;
  }
  out[(size_t)n * DIM + lane] = (float)r;

  float fi = 0.f, fc = 0.f;
#pragma unroll
  for (int i = 0; i < SPAR; ++i)
    if (lane == i) { fi = (float)selI[i]; fc = coefF[i]; }
  if (lane < SPAR) {
    out[(size_t)NPIX * DIM + (size_t)n * SPAR + lane] = fi;
    out[(size_t)NPIX * DIM + (size_t)NPIX * SPAR + (size_t)n * SPAR + lane] = fc;
  }
}

// ---------------------------------------------------------------------------
// Fallback single-wave OMP (tiny-workspace path; R10 kernel). Unchanged.
// ---------------------------------------------------------------------------
__global__ __launch_bounds__(64) void k_omp_fb(const float* __restrict__ X,
                                               const float* __restrict__ D,
                                               const float* __restrict__ G,
                                               const float* __restrict__ Gd,
                                               float* __restrict__ out) {
  const int lane = threadIdx.x & 63;
  const int lane16 = lane * 16;
  const int n = __builtin_amdgcn_readfirstlane(blockIdx.x);

  float hb[16];
  {
    double a[16];
#pragma unroll
    for (int j = 0; j < 16; ++j) a[j] = 0.0;
    for (int d = 0; d < DIM; ++d) {
      float xd = X[(size_t)d * NPIX + n];
#pragma unroll
      for (int j = 0; j < 16; ++j)
        a[j] += (double)xd * (double)D[(size_t)d * NATOM + lane16 + j];
    }
#pragma unroll
    for (int j = 0; j < 16; ++j) hb[j] = (float)a[j];
  }
#pragma unroll
  for (int j = 0; j < 16; ++j) asm volatile("" : "+v"(hb[j]));

  int selI[SPAR];
  float rows[SPAR - 1][16];
  float Lm[SPAR][SPAR], invL[SPAR], ysel[SPAR], coefF[SPAR];

#pragma unroll 8
  for (int s = 0; s < SPAR; ++s) {
    float h[16];
#pragma unroll
    for (int j = 0; j < 16; ++j) {
      float hv = hb[j];
#pragma unroll
      for (int i = 0; i < SPAR - 1; ++i)
        if (i < s) hv = fmaf(-coefF[i], rows[i][j], hv);
      h[j] = hv;
    }
    float m0 = fmaxf(fmaxf(fmaxf(fabsf(h[0]), fabsf(h[1])), fabsf(h[2])), fabsf(h[3]));
    float m1 = fmaxf(fmaxf(fmaxf(fabsf(h[4]), fabsf(h[5])), fabsf(h[6])), fabsf(h[7]));
    float m2 = fmaxf(fmaxf(fmaxf(fabsf(h[8]), fabsf(h[9])), fabsf(h[10])), fabsf(h[11]));
    float m3 = fmaxf(fmaxf(fmaxf(fabsf(h[12]), fabsf(h[13])), fabsf(h[14])), fabsf(h[15]));
    const float M = wave_max_bcast(fmaxf(fmaxf(m0, m1), fmaxf(m2, m3)));
    unsigned cand = NATOM;
#pragma unroll
    for (int j = 15; j >= 0; --j)
      cand = (fabsf(h[j]) == M) ? (unsigned)(lane16 + j) : cand;
    unsigned long long bal = __ballot(cand != (unsigned)NATOM);
    const int fl = __ffsll(bal) - 1;
    const int bk = __builtin_amdgcn_readlane((int)cand, fl);
    selI[s] = bk;
    const int bl = bk >> 4, bj = bk & 15;

    float v = 0.f;
#pragma unroll
    for (int j = 0; j < 16; ++j)
      if (j == bj) v = hb[j];
    const float hbs =
        __int_as_float(__builtin_amdgcn_readlane(__float_as_int(v), bl));

#pragma unroll
    for (int j = 0; j < 16; ++j)
      if (j == bj && lane == bl) hb[j] = __builtin_nanf("");

    if (s < SPAR - 1) {
#pragma unroll
      for (int q = 0; q < 4; ++q) {
        float4 rv = *reinterpret_cast<const float4*>(
            &G[(size_t)bk * NATOM + lane16 + q * 4]);
        rows[s][q * 4 + 0] = rv.x; rows[s][q * 4 + 1] = rv.y;
        rows[s][q * 4 + 2] = rv.z; rows[s][q * 4 + 3] = rv.w;
      }
    }

    const float diag = Gd[bk];
    float w[SPAR];
    float sq = 0.f;
#pragma unroll
    for (int i = 0; i < SPAR; ++i)
      if (i < s) {
        float a = G[(size_t)selI[i] * NATOM + bk];
#pragma unroll
        for (int t = 0; t < SPAR; ++t)
          if (t < i) a = fmaf(-Lm[i][t], w[t], a);
        w[i] = a * invL[i];
        sq += w[i] * w[i];
        Lm[s][i] = w[i];
      }
    float cc = diag - sq;
    if (cc < 1e-6f) cc = 1e-6f;
    invL[s] = 1.0f / sqrtf(cc);
    {
      float a = hbs;
#pragma unroll
      for (int t = 0; t < SPAR; ++t)
        if (t < s) a = fmaf(-Lm[s][t], ysel[t], a);
      ysel[s] = a * invL[s];
    }
#pragma unroll
    for (int i = SPAR - 1; i >= 0; --i)
      if (i <= s) {
        float a = ysel[i];
#pragma unroll
        for (int t = 0; t < SPAR; ++t)
          if (t > i && t <= s) a = fmaf(-Lm[t][i], coefF[t], a);
        coefF[i] = a * invL[i];
      }
    if (s < SPAR - 1) {
#pragma unroll
      for (int j = 0; j < 16; ++j) asm volatile("" : "+v"(rows[s][j]));
    }
  }

  double r = 0.0;
#pragma unroll
  for (int i = 0; i < SPAR; ++i)
    r += (double)coefF[i] * (double)D[(size_t)lane * NATOM + selI[i]];
  out[(size_t)n * DIM + lane] = (float)r;

  float fi = 0.f, fc = 0.f;
#pragma unroll
  for (int i = 0; i < SPAR; ++i)
    if (lane == i) { fi = (float)selI[i]; fc = coefF[i]; }
  if (lane < SPAR) {
    out[(size_t)NPIX * DIM + (size_t)n * SPAR + lane] = fi;
    out[(size_t)NPIX * DIM + (size_t)NPIX * SPAR + (size_t)n * SPAR + lane] = fc;
  }
}

__global__ __launch_bounds__(256) void k_gram(const float* __restrict__ D,
                                              float* __restrict__ G,
                                              float* __restrict__ Gd) {
  int k1 = blockIdx.x;
  __shared__ float d1[DIM];
  if (threadIdx.x < DIM) d1[threadIdx.x] = D[(size_t)threadIdx.x * NATOM + k1];
  __syncthreads();
  for (int k2 = threadIdx.x; k2 < NATOM; k2 += 256) {
    double acc = 0.0;
#pragma unroll
    for (int d = 0; d < DIM; ++d)
      acc += (double)d1[d] * (double)D[(size_t)d * NATOM + k2];
    float g = (float)acc;
    if (k2 == k1) {
      g += 1e-4f;
      Gd[k1] = g;
    }
    G[(size_t)k1 * NATOM + k2] = g;
  }
}

extern "C" void kernel_launch(void* const* d_in, const int* in_sizes, int n_in,
                              void* d_out, int out_size, void* d_ws,
                              size_t ws_size, hipStream_t stream) {
  const float* X = (const float*)d_in[0];  // [64, 16384]
  const float* D = (const float*)d_in[1];  // [64, 1024]
  float* out = (float*)d_out;              // [recon | I | coeffs] as fp32
  float* G = (float*)d_ws;                 // 4 MB
  float* Dt = G + (size_t)NATOM * NATOM;   // 256 KB
  float* Gd = Dt + (size_t)NATOM * DIM;    // 4 KB
  float* HB = Gd + NATOM;                  // 64 MB
  const size_t needFull =
      ((size_t)NATOM * NATOM + (size_t)NATOM * DIM + NATOM +
       (size_t)NPIX * NATOM) * sizeof(float);

  if (ws_size >= needFull) {
    k_pre<<<dim3(1344), dim3(256), 0, stream>>>(X, D, G, Dt, Gd, HB);
    k_omp<true, true><<<dim3(NPIX), dim3(64), 0, stream>>>(
        HB, X, D, Dt, G, Gd, out);
  } else {
    k_gram<<<dim3(NATOM), dim3(256), 0, stream>>>(D, G, Gd);
    k_omp_fb<<<dim3(NPIX), dim3(64), 0, stream>>>(X, D, G, Gd, out);
  }
}

// Round 16
// 96.711 us; speedup vs baseline: 1.4388x; 1.0373x over previous
//
#include <hip/hip_runtime.h>
#include <cmath>

#define NPIX 16384
#define NATOM 1024
#define DIM 64
#define SPAR 8

// ---------------------------------------------------------------------------
// Fused pre-pass, grid-partitioned (1344 blocks) — unchanged (R9-verified):
//   [0,256):    G 64x64 tile = D^T D + 1e-4 I, fp64 acc; Gd diag
//   [256,320):  Dt transpose
//   [320,1344): HB 128n x 128k tile (fp32, 8x8/thread)
// ---------------------------------------------------------------------------
__global__ __launch_bounds__(256) void k_pre(const float* __restrict__ X,
                                             const float* __restrict__ D,
                                             float* __restrict__ G,
                                             float* __restrict__ Dt,
                                             float* __restrict__ Gd,
                                             float* __restrict__ HB) {
  __shared__ float smem[2 * DIM * 128];  // 64 KiB
  const int b = blockIdx.x;
  if (b < 256) {
    const int i0 = (b >> 4) * 64, j0 = (b & 15) * 64;
    float(*sA)[65] = (float(*)[65])smem;
    float(*sB)[65] = (float(*)[65])(smem + DIM * 65);
    for (int t = threadIdx.x; t < DIM * 16; t += 256) {
      int d = t >> 4, c4 = (t & 15) * 4;
      *reinterpret_cast<float4*>(&sA[d][c4]) =
          *reinterpret_cast<const float4*>(&D[(size_t)d * NATOM + i0 + c4]);
      *reinterpret_cast<float4*>(&sB[d][c4]) =
          *reinterpret_cast<const float4*>(&D[(size_t)d * NATOM + j0 + c4]);
    }
    __syncthreads();
    const int ty = (threadIdx.x >> 4) * 4;
    const int tx = (threadIdx.x & 15) * 4;
    double acc[4][4];
#pragma unroll
    for (int ii = 0; ii < 4; ++ii)
#pragma unroll
      for (int jj = 0; jj < 4; ++jj) acc[ii][jj] = 0.0;
    for (int d = 0; d < DIM; ++d) {
      float a[4], bb[4];
#pragma unroll
      for (int ii = 0; ii < 4; ++ii) a[ii] = sA[d][ty + ii];
#pragma unroll
      for (int jj = 0; jj < 4; ++jj) bb[jj] = sB[d][tx + jj];
#pragma unroll
      for (int ii = 0; ii < 4; ++ii)
#pragma unroll
        for (int jj = 0; jj < 4; ++jj)
          acc[ii][jj] += (double)a[ii] * (double)bb[jj];
    }
#pragma unroll
    for (int ii = 0; ii < 4; ++ii)
#pragma unroll
      for (int jj = 0; jj < 4; ++jj) {
        const int k1 = i0 + ty + ii, k2 = j0 + tx + jj;
        float g = (float)acc[ii][jj];
        if (k1 == k2) {
          g += 1e-4f;
          Gd[k1] = g;
        }
        G[(size_t)k1 * NATOM + k2] = g;
      }
  } else if (b < 320) {
    const int base = (b - 256) * 1024 + threadIdx.x * 4;
    float4 v = *reinterpret_cast<const float4*>(&D[base]);
    const float vv[4] = {v.x, v.y, v.z, v.w};
#pragma unroll
    for (int e = 0; e < 4; ++e) {
      int idx = base + e;
      Dt[(size_t)(idx & (NATOM - 1)) * DIM + (idx >> 10)] = vv[e];
    }
  } else {
    const int bx = b - 320;
    const int n0 = (bx & 127) * 128, k0 = (bx >> 7) * 128;
    float(*sX)[128] = (float(*)[128])smem;
    float(*sD)[128] = (float(*)[128])(smem + DIM * 128);
    for (int i = threadIdx.x; i < DIM * 32; i += 256) {
      int d = i >> 5, c4 = (i & 31) * 4;
      *reinterpret_cast<float4*>(&sX[d][c4]) =
          *reinterpret_cast<const float4*>(&X[(size_t)d * NPIX + n0 + c4]);
      *reinterpret_cast<float4*>(&sD[d][c4]) =
          *reinterpret_cast<const float4*>(&D[(size_t)d * NATOM + k0 + c4]);
    }
    __syncthreads();
    const int nl = (threadIdx.x & 15) * 8;
    const int kl = (threadIdx.x >> 4) * 8;
    float acc[8][8];
#pragma unroll
    for (int i = 0; i < 8; ++i)
#pragma unroll
      for (int j = 0; j < 8; ++j) acc[i][j] = 0.f;
#pragma unroll 4
    for (int d = 0; d < DIM; ++d) {
      float xv[8], dv[8];
      *reinterpret_cast<float4*>(&xv[0]) = *reinterpret_cast<float4*>(&sX[d][nl]);
      *reinterpret_cast<float4*>(&xv[4]) = *reinterpret_cast<float4*>(&sX[d][nl + 4]);
      *reinterpret_cast<float4*>(&dv[0]) = *reinterpret_cast<float4*>(&sD[d][kl]);
      *reinterpret_cast<float4*>(&dv[4]) = *reinterpret_cast<float4*>(&sD[d][kl + 4]);
#pragma unroll
      for (int i = 0; i < 8; ++i)
#pragma unroll
        for (int j = 0; j < 8; ++j) acc[i][j] = fmaf(xv[i], dv[j], acc[i][j]);
    }
#pragma unroll
    for (int i = 0; i < 8; ++i)
#pragma unroll
      for (int j = 0; j < 2; ++j)
        *reinterpret_cast<float4*>(
            &HB[(size_t)(n0 + nl + i) * NATOM + k0 + kl + j * 4]) =
            *reinterpret_cast<float4*>(&acc[i][j * 4]);
  }
}

// ---------------------------------------------------------------------------
// DPP wave64 max-reduce (VALU latency, no LDS). HW-verified (rounds 6-15).
// ---------------------------------------------------------------------------
template <int CTRL>
__device__ __forceinline__ float dpp_fmax(float x) {
  int s = __builtin_amdgcn_update_dpp(__float_as_int(x), __float_as_int(x),
                                      CTRL, 0xf, 0xf, false);
  return fmaxf(x, __int_as_float(s));
}
__device__ __forceinline__ float wave_max_bcast(float x) {
  x = dpp_fmax<0x111>(x);  // row_shr:1
  x = dpp_fmax<0x112>(x);  // row_shr:2
  x = dpp_fmax<0x114>(x);  // row_shr:4
  x = dpp_fmax<0x118>(x);  // row_shr:8
  x = dpp_fmax<0x142>(x);  // row_bcast:15
  x = dpp_fmax<0x143>(x);  // row_bcast:31
  return __int_as_float(__builtin_amdgcn_readlane(__float_as_int(x), 63));
}

// force a wave-uniform fp32 value into SGPR allocation (identity on values)
__device__ __forceinline__ float sgprf(float x) {
  return __int_as_float(__builtin_amdgcn_readfirstlane(__float_as_int(x)));
}

// ---------------------------------------------------------------------------
// Batched OMP via Batch-OMP residual recurrence (R15-verified), with the
// wave-uniform solver state (Lm, invL, ysel) forced into SGPRs via
// readfirstlane (identity on uniform values -> numerics bit-identical).
// Frees ~44 VGPRs: target 3 waves/SIMD via __launch_bounds__(64, 3).
// ONE WAVE PER PIXEL, lane owns atoms k = lane*16+j; wr rows pinned in regs.
// Argmax: exact f32 DPP wave-max, descending-j first-match, ballot+ffs.
// NaN-poison h directly. hbs/diag/chol-column via wave-uniform scalar loads.
// ---------------------------------------------------------------------------
template <bool DTW>
__global__ __launch_bounds__(64, 3) void k_omp(const float* __restrict__ HB,
                                               const float* __restrict__ Dt,
                                               const float* __restrict__ D,
                                               const float* __restrict__ G,
                                               const float* __restrict__ Gd,
                                               float* __restrict__ out) {
  const int lane = threadIdx.x & 63;
  const int lane16 = lane * 16;
  const int n = __builtin_amdgcn_readfirstlane(blockIdx.x);

  float h[16];  // residual correlations; starts as h_bar, updated in place
#pragma unroll
  for (int q = 0; q < 4; ++q) {
    float4 v = *reinterpret_cast<const float4*>(
        &HB[(size_t)n * NATOM + lane16 + q * 4]);
    h[q * 4 + 0] = v.x; h[q * 4 + 1] = v.y;
    h[q * 4 + 2] = v.z; h[q * 4 + 3] = v.w;
  }
#pragma unroll
  for (int j = 0; j < 16; ++j) asm volatile("" : "+v"(h[j]));

  int selI[SPAR];            // wave-uniform -> SGPRs
  float wr[SPAR - 1][16];    // wr[t][j] = (L^{-1} G_I)[t][lane16+j], pinned
  float Lm[SPAR][SPAR], invL[SPAR], ysel[SPAR];  // uniform -> SGPR via sgprf

#pragma unroll 8
  for (int s = 0; s < SPAR; ++s) {
    // ---- argmax over |h| (NaN-poisoned slots lose: fmaxf ignores NaN) ----
    float m0 = fmaxf(fmaxf(fabsf(h[0]), fabsf(h[1])), fmaxf(fabsf(h[2]), fabsf(h[3])));
    float m1 = fmaxf(fmaxf(fabsf(h[4]), fabsf(h[5])), fmaxf(fabsf(h[6]), fabsf(h[7])));
    float m2 = fmaxf(fmaxf(fabsf(h[8]), fabsf(h[9])), fmaxf(fabsf(h[10]), fabsf(h[11])));
    float m3 = fmaxf(fmaxf(fabsf(h[12]), fabsf(h[13])), fmaxf(fabsf(h[14]), fabsf(h[15])));
    const float M = wave_max_bcast(fmaxf(fmaxf(m0, m1), fmaxf(m2, m3)));
    unsigned cand = NATOM;
#pragma unroll
    for (int j = 15; j >= 0; --j)
      cand = (fabsf(h[j]) == M) ? (unsigned)(lane16 + j) : cand;
    unsigned long long bal = __ballot(cand != (unsigned)NATOM);
    const int fl = __ffsll(bal) - 1;
    const int bk = __builtin_amdgcn_readlane((int)cand, fl);  // wave-uniform
    selI[s] = bk;
    const int bl = bk >> 4, bj = bk & 15;

    // poison the selected slot: loses every future argmax (NaN semantics)
#pragma unroll
    for (int j = 0; j < 16; ++j)
      if (j == bj && lane == bl) h[j] = __builtin_nanf("");

    // issue G-row fetch early; its waitcnt lands after the scalar chol below
    float g[16];
    if (s < SPAR - 1) {
#pragma unroll
      for (int q = 0; q < 4; ++q) {
        float4 rv = *reinterpret_cast<const float4*>(
            &G[(size_t)bk * NATOM + lane16 + q * 4]);
        g[q * 4 + 0] = rv.x; g[q * 4 + 1] = rv.y;
        g[q * 4 + 2] = rv.z; g[q * 4 + 3] = rv.w;
      }
    }

    // ---- scalar Cholesky column update (wave-uniform loads & math) ----
    const float hbs = HB[(size_t)n * NATOM + bk];  // uniform scalar load
    const float diag = Gd[bk];
    float colv[SPAR];
#pragma unroll
    for (int i = 0; i < SPAR; ++i)
      if (i < s) colv[i] = G[(size_t)selI[i] * NATOM + bk];
    float w[SPAR];
    float sq = 0.f;
#pragma unroll
    for (int i = 0; i < SPAR; ++i)
      if (i < s) {
        float a = colv[i];
#pragma unroll
        for (int t = 0; t < SPAR; ++t)
          if (t < i) a = fmaf(-Lm[i][t], w[t], a);
        w[i] = a * invL[i];
        sq += w[i] * w[i];
        Lm[s][i] = sgprf(w[i]);  // uniform -> SGPR
      }
    float cc = diag - sq;
    if (cc < 1e-6f) cc = 1e-6f;  // jnp.clip(..., CHOL_EPS)
    invL[s] = sgprf(1.0f / sqrtf(cc));

    // ---- y_s (incremental forward solve; earlier entries stable) ----
    {
      float a = hbs;
#pragma unroll
      for (int t = 0; t < SPAR; ++t)
        if (t < s) a = fmaf(-Lm[s][t], ysel[t], a);
      ysel[s] = sgprf(a * invL[s]);
    }

    // ---- build wr_s = (g - sum_t Lm[s][t]*wr_t) * invL[s]; h -= y_s*wr_s --
    if (s < SPAR - 1) {
#pragma unroll
      for (int j = 0; j < 16; ++j) {
        float a = g[j];
#pragma unroll
        for (int t = 0; t < SPAR - 1; ++t)
          if (t < s) a = fmaf(-Lm[s][t], wr[t][j], a);
        float v = a * invL[s];
        wr[s][j] = v;
        h[j] = fmaf(-ysel[s], v, h[j]);
      }
#pragma unroll
      for (int j = 0; j < 16; ++j) asm volatile("" : "+v"(wr[s][j]));
    }
  }

  // ---- final backward solve L^T c = y (op-identical to prior rounds) ----
  float coefF[SPAR];
#pragma unroll
  for (int i = SPAR - 1; i >= 0; --i) {
    float a = ysel[i];
#pragma unroll
    for (int t = 0; t < SPAR; ++t)
      if (t > i) a = fmaf(-Lm[t][i], coefF[t], a);
    coefF[i] = a * invL[i];
  }

  // ---- outputs: recon [n][64], I [n][8], coeffs [n][8] ----
  double r = 0.0;
#pragma unroll
  for (int i = 0; i < SPAR; ++i) {
    float dv = DTW ? Dt[(size_t)selI[i] * DIM + lane]
                   : D[(size_t)lane * NATOM + selI[i]];
    r += (double)coefF[i] * (double)dv;
  }
  out[(size_t)n * DIM + lane] = (float)r;

  float fi = 0.f, fc = 0.f;
#pragma unroll
  for (int i = 0; i < SPAR; ++i)
    if (lane == i) { fi = (float)selI[i]; fc = coefF[i]; }
  if (lane < SPAR) {
    out[(size_t)NPIX * DIM + (size_t)n * SPAR + lane] = fi;
    out[(size_t)NPIX * DIM + (size_t)NPIX * SPAR + (size_t)n * SPAR + lane] = fc;
  }
}

// ---------------------------------------------------------------------------
// Fallback single-wave OMP (tiny-workspace path; R10 kernel). Unchanged.
// ---------------------------------------------------------------------------
__global__ __launch_bounds__(64) void k_omp_fb(const float* __restrict__ X,
                                               const float* __restrict__ D,
                                               const float* __restrict__ G,
                                               const float* __restrict__ Gd,
                                               float* __restrict__ out) {
  const int lane = threadIdx.x & 63;
  const int lane16 = lane * 16;
  const int n = __builtin_amdgcn_readfirstlane(blockIdx.x);

  float hb[16];
  {
    double a[16];
#pragma unroll
    for (int j = 0; j < 16; ++j) a[j] = 0.0;
    for (int d = 0; d < DIM; ++d) {
      float xd = X[(size_t)d * NPIX + n];
#pragma unroll
      for (int j = 0; j < 16; ++j)
        a[j] += (double)xd * (double)D[(size_t)d * NATOM + lane16 + j];
    }
#pragma unroll
    for (int j = 0; j < 16; ++j) hb[j] = (float)a[j];
  }
#pragma unroll
  for (int j = 0; j < 16; ++j) asm volatile("" : "+v"(hb[j]));

  int selI[SPAR];
  float rows[SPAR - 1][16];
  float Lm[SPAR][SPAR], invL[SPAR], ysel[SPAR], coefF[SPAR];

#pragma unroll 8
  for (int s = 0; s < SPAR; ++s) {
    float h[16];
#pragma unroll
    for (int j = 0; j < 16; ++j) {
      float hv = hb[j];
#pragma unroll
      for (int i = 0; i < SPAR - 1; ++i)
        if (i < s) hv = fmaf(-coefF[i], rows[i][j], hv);
      h[j] = hv;
    }
    float m0 = fmaxf(fmaxf(fmaxf(fabsf(h[0]), fabsf(h[1])), fabsf(h[2])), fabsf(h[3]));
    float m1 = fmaxf(fmaxf(fmaxf(fabsf(h[4]), fabsf(h[5])), fabsf(h[6])), fabsf(h[7]));
    float m2 = fmaxf(fmaxf(fmaxf(fabsf(h[8]), fabsf(h[9])), fabsf(h[10])), fabsf(h[11]));
    float m3 = fmaxf(fmaxf(fmaxf(fabsf(h[12]), fabsf(h[13])), fabsf(h[14])), fabsf(h[15]));
    const float M = wave_max_bcast(fmaxf(fmaxf(m0, m1), fmaxf(m2, m3)));
    unsigned cand = NATOM;
#pragma unroll
    for (int j = 15; j >= 0; --j)
      cand = (fabsf(h[j]) == M) ? (unsigned)(lane16 + j) : cand;
    unsigned long long bal = __ballot(cand != (unsigned)NATOM);
    const int fl = __ffsll(bal) - 1;
    const int bk = __builtin_amdgcn_readlane((int)cand, fl);
    selI[s] = bk;
    const int bl = bk >> 4, bj = bk & 15;

    float v = 0.f;
#pragma unroll
    for (int j = 0; j < 16; ++j)
      if (j == bj) v = hb[j];
    const float hbs =
        __int_as_float(__builtin_amdgcn_readlane(__float_as_int(v), bl));

#pragma unroll
    for (int j = 0; j < 16; ++j)
      if (j == bj && lane == bl) hb[j] = __builtin_nanf("");

    if (s < SPAR - 1) {
#pragma unroll
      for (int q = 0; q < 4; ++q) {
        float4 rv = *reinterpret_cast<const float4*>(
            &G[(size_t)bk * NATOM + lane16 + q * 4]);
        rows[s][q * 4 + 0] = rv.x; rows[s][q * 4 + 1] = rv.y;
        rows[s][q * 4 + 2] = rv.z; rows[s][q * 4 + 3] = rv.w;
      }
    }

    const float diag = Gd[bk];
    float w[SPAR];
    float sq = 0.f;
#pragma unroll
    for (int i = 0; i < SPAR; ++i)
      if (i < s) {
        float a = G[(size_t)selI[i] * NATOM + bk];
#pragma unroll
        for (int t = 0; t < SPAR; ++t)
          if (t < i) a = fmaf(-Lm[i][t], w[t], a);
        w[i] = a * invL[i];
        sq += w[i] * w[i];
        Lm[s][i] = w[i];
      }
    float cc = diag - sq;
    if (cc < 1e-6f) cc = 1e-6f;
    invL[s] = 1.0f / sqrtf(cc);
    {
      float a = hbs;
#pragma unroll
      for (int t = 0; t < SPAR; ++t)
        if (t < s) a = fmaf(-Lm[s][t], ysel[t], a);
      ysel[s] = a * invL[s];
    }
#pragma unroll
    for (int i = SPAR - 1; i >= 0; --i)
      if (i <= s) {
        float a = ysel[i];
#pragma unroll
        for (int t = 0; t < SPAR; ++t)
          if (t > i && t <= s) a = fmaf(-Lm[t][i], coefF[t], a);
        coefF[i] = a * invL[i];
      }
    if (s < SPAR - 1) {
#pragma unroll
      for (int j = 0; j < 16; ++j) asm volatile("" : "+v"(rows[s][j]));
    }
  }

  double r = 0.0;
#pragma unroll
  for (int i = 0; i < SPAR; ++i)
    r += (double)coefF[i] * (double)D[(size_t)lane * NATOM + selI[i]];
  out[(size_t)n * DIM + lane] = (float)r;

  float fi = 0.f, fc = 0.f;
#pragma unroll
  for (int i = 0; i < SPAR; ++i)
    if (lane == i) { fi = (float)selI[i]; fc = coefF[i]; }
  if (lane < SPAR) {
    out[(size_t)NPIX * DIM + (size_t)n * SPAR + lane] = fi;
    out[(size_t)NPIX * DIM + (size_t)NPIX * SPAR + (size_t)n * SPAR + lane] = fc;
  }
}

__global__ __launch_bounds__(256) void k_gram(const float* __restrict__ D,
                                              float* __restrict__ G,
                                              float* __restrict__ Gd) {
  int k1 = blockIdx.x;
  __shared__ float d1[DIM];
  if (threadIdx.x < DIM) d1[threadIdx.x] = D[(size_t)threadIdx.x * NATOM + k1];
  __syncthreads();
  for (int k2 = threadIdx.x; k2 < NATOM; k2 += 256) {
    double acc = 0.0;
#pragma unroll
    for (int d = 0; d < DIM; ++d)
      acc += (double)d1[d] * (double)D[(size_t)d * NATOM + k2];
    float g = (float)acc;
    if (k2 == k1) {
      g += 1e-4f;
      Gd[k1] = g;
    }
    G[(size_t)k1 * NATOM + k2] = g;
  }
}

extern "C" void kernel_launch(void* const* d_in, const int* in_sizes, int n_in,
                              void* d_out, int out_size, void* d_ws,
                              size_t ws_size, hipStream_t stream) {
  const float* X = (const float*)d_in[0];  // [64, 16384]
  const float* D = (const float*)d_in[1];  // [64, 1024]
  float* out = (float*)d_out;              // [recon | I | coeffs] as fp32
  float* G = (float*)d_ws;                 // 4 MB
  float* Dt = G + (size_t)NATOM * NATOM;   // 256 KB
  float* Gd = Dt + (size_t)NATOM * DIM;    // 4 KB
  float* HB = Gd + NATOM;                  // 64 MB
  const size_t needFull =
      ((size_t)NATOM * NATOM + (size_t)NATOM * DIM + NATOM +
       (size_t)NPIX * NATOM) * sizeof(float);

  if (ws_size >= needFull) {
    k_pre<<<dim3(1344), dim3(256), 0, stream>>>(X, D, G, Dt, Gd, HB);
    k_omp<true><<<dim3(NPIX), dim3(64), 0, stream>>>(HB, Dt, D, G, Gd, out);
  } else {
    k_gram<<<dim3(NATOM), dim3(256), 0, stream>>>(D, G, Gd);
    k_omp_fb<<<dim3(NPIX), dim3(64), 0, stream>>>(X, D, G, Gd, out);
  }
}